// Round 2
// baseline (112.352 us; speedup 1.0000x reference)
//
#include <hip/hip_runtime.h>

// Reference returns (x, y) unchanged — _block_scores is computed and discarded.
// d_out = concat(flat(x), flat(y)) in float32. Pure D2D copy, memory-bound.
// 268 MB read + 268 MB write -> ~85 us at ~6.3 TB/s achievable HBM BW.
// Single float4 grid-stride kernel beats two serialized memcpy blits.

__global__ __launch_bounds__(256)
void copy_xy_kernel(const float4* __restrict__ x, const float4* __restrict__ y,
                    float4* __restrict__ ox, float4* __restrict__ oy,
                    size_t n4x, size_t n4y) {
    const size_t stride = (size_t)gridDim.x * blockDim.x;
    size_t i0 = (size_t)blockIdx.x * blockDim.x + threadIdx.x;
    for (size_t i = i0; i < n4x; i += stride) ox[i] = x[i];
    for (size_t i = i0; i < n4y; i += stride) oy[i] = y[i];
}

extern "C" void kernel_launch(void* const* d_in, const int* in_sizes, int n_in,
                              void* d_out, int out_size, void* d_ws, size_t ws_size,
                              hipStream_t stream) {
    const size_t nx = (size_t)in_sizes[0];  // x: 128*64*64*64 f32
    const size_t ny = (size_t)in_sizes[1];  // y: 128*64*64*64 f32
    const size_t n4x = nx / 4, n4y = ny / 4;   // both divisible by 4

    const float4* x = (const float4*)d_in[0];
    const float4* y = (const float4*)d_in[1];
    float4* ox = (float4*)d_out;
    float4* oy = (float4*)((char*)d_out + nx * sizeof(float));

    copy_xy_kernel<<<2048, 256, 0, stream>>>(x, y, ox, oy, n4x, n4y);
}

// Round 4
// 99.698 us; speedup vs baseline: 1.1269x; 1.1269x over previous
//
#include <hip/hip_runtime.h>

// Reference returns (x, y) unchanged — _block_scores is computed and discarded.
// d_out = concat(flat(x), flat(y)) in float32. Pure D2D copy, memory-bound.
// 268 MB read + 268 MB write; working set (537 MB) > L3 (256 MB) -> stream
// with nontemporal load/store (nt flag) to avoid cache thrash.
// Native ext_vector type: __builtin_nontemporal_* rejects HIP_vector_type.

typedef float f4 __attribute__((ext_vector_type(4)));

__global__ __launch_bounds__(256)
void copy_xy_kernel(const f4* __restrict__ x, const f4* __restrict__ y,
                    f4* __restrict__ ox, f4* __restrict__ oy,
                    size_t n4x, size_t n4y) {
    const size_t stride = (size_t)gridDim.x * blockDim.x;
    size_t i0 = (size_t)blockIdx.x * blockDim.x + threadIdx.x;
    const size_t n4m = n4x > n4y ? n4x : n4y;
    for (size_t i = i0; i < n4m; i += stride) {
        if (i < n4x) {
            f4 a = __builtin_nontemporal_load(&x[i]);
            __builtin_nontemporal_store(a, &ox[i]);
        }
        if (i < n4y) {
            f4 b = __builtin_nontemporal_load(&y[i]);
            __builtin_nontemporal_store(b, &oy[i]);
        }
    }
}

extern "C" void kernel_launch(void* const* d_in, const int* in_sizes, int n_in,
                              void* d_out, int out_size, void* d_ws, size_t ws_size,
                              hipStream_t stream) {
    const size_t nx = (size_t)in_sizes[0];  // x: 128*64*64*64 f32
    const size_t ny = (size_t)in_sizes[1];  // y: 128*64*64*64 f32
    const size_t n4x = nx / 4, n4y = ny / 4;

    const f4* x = (const f4*)d_in[0];
    const f4* y = (const f4*)d_in[1];
    f4* ox = (f4*)d_out;
    f4* oy = (f4*)((char*)d_out + nx * sizeof(float));

    copy_xy_kernel<<<2048, 256, 0, stream>>>(x, y, ox, oy, n4x, n4y);
}